// Round 4
// baseline (652.066 us; speedup 1.0000x reference)
//
#include <hip/hip_runtime.h>
#include <math.h>

// B=8, C=64, T=128, E=256, 4E=1024, TYPE_NUM=40, NF=128
// h_pre[b,c,t,:] = Apre[c,:] + [ctx, |q-ctx|, q*ctx] @ Wh[:,256:1024]^T (K=768 MFMA)
// attn v5: register-prefetch software pipeline (global loads for chunk k+1 issued
// before MFMA on chunk k; barrier drain finds loads already landed).
// conv v2: pre-transposed weights + LDS-staged x, partials over e-chunks.

typedef __bf16 bf16x8 __attribute__((ext_vector_type(8)));
typedef float  f32x4  __attribute__((ext_vector_type(4)));

__device__ __forceinline__ float ftanh(float v) {
    float t = __expf(2.f * v);
    return 1.f - 2.f * __builtin_amdgcn_rcpf(t + 1.f);
}

// ---------------- fp32 tiled GEMM (only for Apre: M=64,N=1024,K=256) ----------------
__global__ __launch_bounds__(256) void gemm_tn_kernel(
    const float* __restrict__ A, int lda,
    const float* __restrict__ B, int ldb,
    const float* __restrict__ bias,
    float* __restrict__ C, int ldc, int K)
{
    __shared__ float As[16][68];
    __shared__ float Bs[16][68];
    const int tid = threadIdx.x;
    const int m0 = blockIdx.y * 64, n0 = blockIdx.x * 64;
    const int tm = tid >> 4, tn = tid & 15;
    const int lr = tid >> 2;
    const int lc = (tid & 3) * 4;

    float acc[4][4];
#pragma unroll
    for (int i = 0; i < 4; ++i)
#pragma unroll
        for (int j = 0; j < 4; ++j) acc[i][j] = 0.f;

    for (int k0 = 0; k0 < K; k0 += 16) {
        float4 av = *reinterpret_cast<const float4*>(A + (size_t)(m0 + lr) * lda + k0 + lc);
        float4 bv = *reinterpret_cast<const float4*>(B + (size_t)(n0 + lr) * ldb + k0 + lc);
        As[lc + 0][lr] = av.x; As[lc + 1][lr] = av.y; As[lc + 2][lr] = av.z; As[lc + 3][lr] = av.w;
        Bs[lc + 0][lr] = bv.x; Bs[lc + 1][lr] = bv.y; Bs[lc + 2][lr] = bv.z; Bs[lc + 3][lr] = bv.w;
        __syncthreads();
#pragma unroll
        for (int kk = 0; kk < 16; ++kk) {
            float4 a = *reinterpret_cast<const float4*>(&As[kk][tm * 4]);
            float4 b = *reinterpret_cast<const float4*>(&Bs[kk][tn * 4]);
            float ar[4] = {a.x, a.y, a.z, a.w};
            float br[4] = {b.x, b.y, b.z, b.w};
#pragma unroll
            for (int i = 0; i < 4; ++i)
#pragma unroll
                for (int j = 0; j < 4; ++j) acc[i][j] += ar[i] * br[j];
        }
        __syncthreads();
    }

#pragma unroll
    for (int i = 0; i < 4; ++i) {
        int m = m0 + tm * 4 + i;
        float vals[4];
#pragma unroll
        for (int j = 0; j < 4; ++j) {
            int n = n0 + tn * 4 + j;
            vals[j] = acc[i][j] + (bias ? bias[n] : 0.f);
        }
        float4 o; o.x = vals[0]; o.y = vals[1]; o.z = vals[2]; o.w = vals[3];
        *reinterpret_cast<float4*>(C + (size_t)m * ldc + n0 + tn * 4) = o;
    }
}

// ---------------- one-shot conversions: bf16 weights + transposed conv weights -----
__global__ void cvt_kernel(const float* __restrict__ Wh, const float* __restrict__ Wl,
                           const float* __restrict__ cw0, const float* __restrict__ cw1,
                           const float* __restrict__ cw2,
                           __bf16* __restrict__ Whbf, __bf16* __restrict__ Wlbf,
                           float* __restrict__ wt0, float* __restrict__ wt1,
                           float* __restrict__ wt2)
{
    int idx = blockIdx.x * 256 + threadIdx.x;   // < 1703936
    if (idx < 1048576) { Whbf[idx] = (__bf16)Wh[idx]; return; }
    if (idx < 1310720) { Wlbf[idx - 1048576] = (__bf16)Wl[idx - 1048576]; return; }
    if (idx < 1474560) {            // wt0[(e*5+i)*128+f] = cw0[(f*256+e)*5+i]
        int j = idx - 1310720; int f = j & 127, rest = j >> 7;
        int i = rest % 5, e = rest / 5;
        wt0[j] = cw0[(size_t)(f * 256 + e) * 5 + i]; return;
    }
    if (idx < 1605632) {
        int j = idx - 1474560; int f = j & 127, rest = j >> 7;
        int i = rest & 3, e = rest >> 2;
        wt1[j] = cw1[(size_t)(f * 256 + e) * 4 + i]; return;
    }
    {
        int j = idx - 1605632; int f = j & 127, rest = j >> 7;
        int i = rest % 3, e = rest / 3;
        wt2[j] = cw2[(size_t)(f * 256 + e) * 3 + i];
    }
}

// ---------------- attn v5: pipelined bf16-MFMA K=768 + tanh + Wv + softmax + g -----
__global__ __launch_bounds__(256, 2) void attn_kernel(
    const float* __restrict__ q,      // [64][256]
    const float* __restrict__ ctx,    // [8][128][256] fp32
    const int*   __restrict__ mask,   // [8][128]
    const __bf16* __restrict__ Whbf,  // [1024][1024] bf16
    const float* __restrict__ Wv,     // [1024]
    const float* __restrict__ bv,     // [1]
    const float* __restrict__ Apre,   // [64][1024] (includes b_hidden)
    float* __restrict__ g)            // [512][256]
{
    __shared__ __bf16 Us[128 * 72];
    __shared__ __bf16 Ws[256 * 72];
    __shared__ float qc[256];
    __shared__ float sc[128];
    __shared__ float red;

    const int tid = threadIdx.x;
    const int b = blockIdx.x >> 6, c = blockIdx.x & 63;
    const int wave = tid >> 6, lane = tid & 63;
    const int w0 = wave >> 1, w1 = wave & 1;
    const int m0 = w0 * 64;
    const int l15 = lane & 15, quad = lane >> 4;

    // staging indices (fixed per thread)
    const int wrow = tid >> 3, wkg = tid & 7;         // Ws granule base (8 iters)
    const int urow = tid >> 3, ukg = tid & 7;         // Us: only 4 iters (idx<1024)

    qc[tid] = q[c * 256 + tid];
    if (tid < 128) sc[tid] = 0.f;
    __syncthreads();

    for (int nc = 0; nc < 4; ++nc) {
        f32x4 acc[4][8];
#pragma unroll
        for (int mi = 0; mi < 4; ++mi)
#pragma unroll
            for (int ni = 0; ni < 8; ++ni) acc[mi][ni] = (f32x4){0.f, 0.f, 0.f, 0.f};

        // ---- prologue: stage chunk 0 ----
        {
            const int kc = 0;
#pragma unroll
            for (int it = 0; it < 8; ++it) {
                int row = wrow + it * 32;
                int4 v = *reinterpret_cast<const int4*>(
                    Whbf + ((size_t)(nc * 256 + row) * 1024 + 256 + kc * 64 + wkg * 8));
                *reinterpret_cast<int4*>(&Ws[row * 72 + wkg * 8]) = v;
            }
            const int region = kc >> 2, e00 = (kc & 3) * 64;
#pragma unroll
            for (int it = 0; it < 4; ++it) {
                int t = urow + it * 32;
                int eb = e00 + ukg * 8;
                const float* cp = ctx + (size_t)(b * 128 + t) * 256 + eb;
                float4 c0 = *reinterpret_cast<const float4*>(cp);
                float4 c1 = *reinterpret_cast<const float4*>(cp + 4);
                float cv[8] = {c0.x, c0.y, c0.z, c0.w, c1.x, c1.y, c1.z, c1.w};
                bf16x8 u;
#pragma unroll
                for (int i = 0; i < 8; ++i) {
                    float qv = qc[eb + i];
                    float x = (region == 0) ? cv[i] : (region == 1) ? fabsf(qv - cv[i]) : qv * cv[i];
                    u[i] = (__bf16)x;
                }
                *reinterpret_cast<bf16x8*>(&Us[t * 72 + ukg * 8]) = u;
            }
        }
        __syncthreads();

        for (int kc = 0; kc < 12; ++kc) {
            // ---- phase A: prefetch chunk kc+1 into registers ----
            int4 wreg[8];
            float4 ureg[4];                 // U granules 0,1 (2 x float4 each)
            const int kn = kc + 1;
            const bool havenext = (kn < 12);
            if (havenext) {
#pragma unroll
                for (int it = 0; it < 8; ++it) {
                    int row = wrow + it * 32;
                    wreg[it] = *reinterpret_cast<const int4*>(
                        Whbf + ((size_t)(nc * 256 + row) * 1024 + 256 + kn * 64 + wkg * 8));
                }
                const int e0n = (kn & 3) * 64;
#pragma unroll
                for (int it = 0; it < 2; ++it) {
                    int t = urow + it * 32;
                    const float* cp = ctx + (size_t)(b * 128 + t) * 256 + e0n + ukg * 8;
                    ureg[it * 2 + 0] = *reinterpret_cast<const float4*>(cp);
                    ureg[it * 2 + 1] = *reinterpret_cast<const float4*>(cp + 4);
                }
            }
            // ---- phase B: MFMA on chunk kc (in LDS) ----
#pragma unroll
            for (int ks = 0; ks < 2; ++ks) {
                bf16x8 a[4], bf[8];
#pragma unroll
                for (int mi = 0; mi < 4; ++mi)
                    a[mi] = *reinterpret_cast<const bf16x8*>(
                        &Us[(m0 + mi * 16 + l15) * 72 + ks * 32 + quad * 8]);
#pragma unroll
                for (int ni = 0; ni < 8; ++ni)
                    bf[ni] = *reinterpret_cast<const bf16x8*>(
                        &Ws[(w1 * 128 + ni * 16 + l15) * 72 + ks * 32 + quad * 8]);
#pragma unroll
                for (int mi = 0; mi < 4; ++mi)
#pragma unroll
                    for (int ni = 0; ni < 8; ++ni)
                        acc[mi][ni] = __builtin_amdgcn_mfma_f32_16x16x32_bf16(
                            a[mi], bf[ni], acc[mi][ni], 0, 0, 0);
            }
            __syncthreads();                 // all waves done reading chunk kc
            // ---- phase D: write chunk kc+1 ----
            if (havenext) {
                const int regionN = kn >> 2, e0n = (kn & 3) * 64;
                // issue remaining U loads (granules 2,3) first to overlap with cvt below
                float4 u2[4];
#pragma unroll
                for (int it = 0; it < 2; ++it) {
                    int t = urow + (it + 2) * 32;
                    const float* cp = ctx + (size_t)(b * 128 + t) * 256 + e0n + ukg * 8;
                    u2[it * 2 + 0] = *reinterpret_cast<const float4*>(cp);
                    u2[it * 2 + 1] = *reinterpret_cast<const float4*>(cp + 4);
                }
#pragma unroll
                for (int it = 0; it < 8; ++it) {
                    int row = wrow + it * 32;
                    *reinterpret_cast<int4*>(&Ws[row * 72 + wkg * 8]) = wreg[it];
                }
#pragma unroll
                for (int it = 0; it < 4; ++it) {
                    int t = urow + (it & 1) * 32 + (it >> 1) * 64;  // 0,32,64,96
                    float4 c0 = (it < 2) ? ureg[it * 2] : u2[(it - 2) * 2];
                    float4 c1 = (it < 2) ? ureg[it * 2 + 1] : u2[(it - 2) * 2 + 1];
                    // NOTE: granule rows must match load rows: loads used t=urow+{0,32,64,96}
                    float cv[8] = {c0.x, c0.y, c0.z, c0.w, c1.x, c1.y, c1.z, c1.w};
                    int eb = e0n + ukg * 8;
                    bf16x8 u;
#pragma unroll
                    for (int i = 0; i < 8; ++i) {
                        float qv = qc[eb + i];
                        float x = (regionN == 0) ? cv[i]
                                : (regionN == 1) ? fabsf(qv - cv[i]) : qv * cv[i];
                        u[i] = (__bf16)x;
                    }
                    *reinterpret_cast<bf16x8*>(&Us[t * 72 + ukg * 8]) = u;
                }
                __syncthreads();             // chunk kc+1 visible for next iter
            }
        }

        // ---- epilogue: h = ftanh(acc + Apre), partial score = h . Wv ----
        const int jcol = nc * 256 + w1 * 128 + l15;
        float av[8], wv[8];
#pragma unroll
        for (int ni = 0; ni < 8; ++ni) {
            av[ni] = Apre[c * 1024 + jcol + ni * 16];
            wv[ni] = Wv[jcol + ni * 16];
        }
#pragma unroll
        for (int mi = 0; mi < 4; ++mi) {
            const int tbase = m0 + mi * 16 + quad * 4;
            float p[4];
#pragma unroll
            for (int r = 0; r < 4; ++r) {
                float s = 0.f;
#pragma unroll
                for (int ni = 0; ni < 8; ++ni)
                    s += ftanh(acc[mi][ni][r] + av[ni]) * wv[ni];
                p[r] = s;
            }
#pragma unroll
            for (int off = 1; off < 16; off <<= 1)
#pragma unroll
                for (int r = 0; r < 4; ++r) p[r] += __shfl_xor(p[r], off, 16);
            if (l15 == 0) {
#pragma unroll
                for (int r = 0; r < 4; ++r) atomicAdd(&sc[tbase + r], p[r]);
            }
        }
        __syncthreads();                     // epilogue done before next prologue writes
    }

    // mask + b_v, softmax over t
    if (tid < 128) {
        float s = sc[tid] + bv[0];
        if (mask[b * 128 + tid] < 1) s = -1e10f;
        sc[tid] = s;
    }
    __syncthreads();
    if (tid < 64) {
        float m = fmaxf(sc[tid], sc[tid + 64]);
        for (int off = 32; off; off >>= 1) m = fmaxf(m, __shfl_xor(m, off, 64));
        if (tid == 0) red = m;
    }
    __syncthreads();
    const float mx = red;
    if (tid < 128) sc[tid] = __expf(sc[tid] - mx);
    __syncthreads();
    if (tid < 64) {
        float s = sc[tid] + sc[tid + 64];
        for (int off = 32; off; off >>= 1) s += __shfl_xor(s, off, 64);
        if (tid == 0) red = s;
    }
    __syncthreads();
    const float inv = 1.f / red;

    float gv = 0.f;
    for (int t = 0; t < 128; ++t) gv += sc[t] * ctx[(size_t)(b * 128 + t) * 256 + tid];
    g[(size_t)blockIdx.x * 256 + tid] = gv * inv;
}

// ---------------- feat2 = [g, |q-g|, q*g] (768 cols, bf16) ----------------
__global__ void feat2_kernel(const float* __restrict__ q, const float* __restrict__ g,
                             __bf16* __restrict__ feat2)
{
    int row = blockIdx.x, e = threadIdx.x;
    int c = row & 63;
    float qv = q[c * 256 + e], gv = g[row * 256 + e];
    __bf16* o = feat2 + (size_t)row * 768 + e;
    o[0]   = (__bf16)gv;
    o[256] = (__bf16)fabsf(qv - gv);
    o[512] = (__bf16)(qv * gv);
}

// ---------------- bf16 MFMA GEMM: C = act(A @ B^T + bias), 64x64 tile ----------------
// BMODE 0: bias[col]; BMODE 1: bias[(row&63)*1024 + col] (Apre-style)
template <int ACT, int OUTBF, int BMODE>
__global__ __launch_bounds__(256) void mfma_gemm_kernel(
    const __bf16* __restrict__ A, int lda,
    const __bf16* __restrict__ B, int ldb,
    const float* __restrict__ bias, void* __restrict__ Cout,
    int K, int ldc)
{
    __shared__ __bf16 As[64 * 72];
    __shared__ __bf16 Bs[64 * 72];
    const int tid = threadIdx.x;
    const int wave = tid >> 6, lane = tid & 63;
    const int w0 = wave >> 1, w1 = wave & 1;
    const int l15 = lane & 15, quad = lane >> 4;
    const int m0 = blockIdx.y * 64, n0 = blockIdx.x * 64;

    f32x4 acc[2][2];
#pragma unroll
    for (int mi = 0; mi < 2; ++mi)
#pragma unroll
        for (int ni = 0; ni < 2; ++ni) acc[mi][ni] = (f32x4){0.f, 0.f, 0.f, 0.f};

    for (int k0 = 0; k0 < K; k0 += 64) {
        __syncthreads();
#pragma unroll
        for (int it = 0; it < 2; ++it) {
            int idx = tid + it * 256;
            int row = idx >> 3, kg = idx & 7;
            int4 va = *reinterpret_cast<const int4*>(A + (size_t)(m0 + row) * lda + k0 + kg * 8);
            *reinterpret_cast<int4*>(&As[row * 72 + kg * 8]) = va;
            int4 vb = *reinterpret_cast<const int4*>(B + (size_t)(n0 + row) * ldb + k0 + kg * 8);
            *reinterpret_cast<int4*>(&Bs[row * 72 + kg * 8]) = vb;
        }
        __syncthreads();
#pragma unroll
        for (int ks = 0; ks < 2; ++ks) {
            bf16x8 a[2], bb[2];
#pragma unroll
            for (int mi = 0; mi < 2; ++mi)
                a[mi] = *reinterpret_cast<const bf16x8*>(
                    &As[(w0 * 32 + mi * 16 + l15) * 72 + ks * 32 + quad * 8]);
#pragma unroll
            for (int ni = 0; ni < 2; ++ni)
                bb[ni] = *reinterpret_cast<const bf16x8*>(
                    &Bs[(w1 * 32 + ni * 16 + l15) * 72 + ks * 32 + quad * 8]);
#pragma unroll
            for (int mi = 0; mi < 2; ++mi)
#pragma unroll
                for (int ni = 0; ni < 2; ++ni)
                    acc[mi][ni] = __builtin_amdgcn_mfma_f32_16x16x32_bf16(
                        a[mi], bb[ni], acc[mi][ni], 0, 0, 0);
        }
    }

#pragma unroll
    for (int mi = 0; mi < 2; ++mi)
#pragma unroll
        for (int ni = 0; ni < 2; ++ni) {
            int col = n0 + w1 * 32 + ni * 16 + l15;
#pragma unroll
            for (int r = 0; r < 4; ++r) {
                int row = m0 + w0 * 32 + mi * 16 + quad * 4 + r;
                float bsv = (BMODE == 0) ? bias[col] : bias[(row & 63) * 1024 + col];
                float v = acc[mi][ni][r] + bsv;
                if (ACT) v = ftanh(v);
                if (OUTBF) ((__bf16*)Cout)[(size_t)row * ldc + col] = (__bf16)v;
                else       ((float*)Cout)[(size_t)row * ldc + col] = v;
            }
        }
}

// ---------------- conv v2: e-chunk partials ----------------
// grid 96 = kw(3) x b(8) x chunk(4 of 64 e). 256 thr = (f=tid&127, esub=tid>>7).
// part[(bi*2+esub)][p][f] = partial conv sum over the thread's 32-e range.
template <int KW>
__device__ __forceinline__ void conv_body(
    const float* __restrict__ x, const float* __restrict__ wt,
    float* __restrict__ part, int b, int chunk, int bi, float* xs)
{
    const int tid = threadIdx.x;
    const int f = tid & 127, esub = tid >> 7;
    const int e0 = chunk * 64;

    // stage xs[e][p] (stride 72) for 64 e x 64 p
#pragma unroll
    for (int it = 0; it < 16; ++it) {
        int idx = tid + it * 256;
        int e = idx & 63, p = idx >> 6;
        xs[e * 72 + p] = x[(size_t)(b * 64 + p) * 256 + e0 + e];
    }
    __syncthreads();

    float acc[64];
#pragma unroll
    for (int p = 0; p < 64; ++p) acc[p] = 0.f;

    for (int ei = 0; ei < 32; ++ei) {
        const int eL = esub * 32 + ei;
        float wreg[KW];
#pragma unroll
        for (int i = 0; i < KW; ++i)
            wreg[i] = wt[(size_t)((e0 + eL) * KW + i) * 128 + f];
        float xv[68];
#pragma unroll
        for (int k4 = 0; k4 < 17; ++k4) {
            float4 v = *reinterpret_cast<const float4*>(&xs[eL * 72 + k4 * 4]);
            xv[k4 * 4 + 0] = v.x; xv[k4 * 4 + 1] = v.y;
            xv[k4 * 4 + 2] = v.z; xv[k4 * 4 + 3] = v.w;
        }
#pragma unroll
        for (int i = 0; i < KW; ++i)
#pragma unroll
            for (int p = 0; p < 64; ++p)
                acc[p] = fmaf(wreg[i], xv[p + i], acc[p]);
    }

    float* op = part + ((size_t)(bi * 2 + esub)) * 8192 + f;
#pragma unroll
    for (int p = 0; p < 64; ++p) op[p * 128] = acc[p];
}

__global__ __launch_bounds__(256) void conv_partial_kernel(
    const float* __restrict__ x,
    const float* __restrict__ wt0, const float* __restrict__ wt1,
    const float* __restrict__ wt2, float* __restrict__ part)
{
    __shared__ float xs[64 * 72];
    const int bi = blockIdx.x;            // kw*32 + b*4 + chunk
    const int kw = bi >> 5, b = (bi >> 2) & 7, chunk = bi & 3;
    if (kw == 0)      conv_body<5>(x, wt0, part, b, chunk, bi, xs);
    else if (kw == 1) conv_body<4>(x, wt1, part, b, chunk, bi, xs);
    else              conv_body<3>(x, wt2, part, b, chunk, bi, xs);
}

// ---------------- reduce partials + bias + relu + maxpool ----------------
__global__ __launch_bounds__(128) void reduce_pool_kernel(
    const float* __restrict__ part,
    const float* __restrict__ b0, const float* __restrict__ b1,
    const float* __restrict__ b2, float* __restrict__ cnn)
{
    const int bi = blockIdx.x;            // kw*8 + b
    const int kw = bi >> 3, b = bi & 7;
    const int f = threadIdx.x;
    const int KW = 5 - kw, P = 64 - KW + 1;
    const float bias = (kw == 0 ? b0 : kw == 1 ? b1 : b2)[f];
    float mx = 0.f;                        // relu floor
    for (int p = 0; p < P; ++p) {
        float s = 0.f;
#pragma unroll
        for (int c4 = 0; c4 < 4; ++c4)
#pragma unroll
            for (int es = 0; es < 2; ++es)
                s += part[((size_t)((kw * 32 + b * 4 + c4) * 2 + es)) * 8192 + p * 128 + f];
        s += bias;
        mx = fmaxf(mx, s);
    }
    cnn[b * 384 + kw * 128 + f] = mx;
}

// ---------------- final FC ----------------
__global__ void final_kernel(const float* __restrict__ cnn, const float* __restrict__ Wc,
                             const float* __restrict__ bc, float* __restrict__ out)
{
    int o = threadIdx.x;
    if (o >= 320) return;
    int b = o / 40, t = o - b * 40;
    float s = bc[t];
    for (int i = 0; i < 384; ++i) s += cnn[b * 384 + i] * Wc[t * 384 + i];
    out[o] = s;
}

extern "C" void kernel_launch(void* const* d_in, const int* in_sizes, int n_in,
                              void* d_out, int out_size, void* d_ws, size_t ws_size,
                              hipStream_t stream)
{
    (void)in_sizes; (void)n_in; (void)out_size; (void)ws_size;
    const float* q    = (const float*)d_in[0];
    const float* ctx  = (const float*)d_in[1];
    const int*   mask = (const int*)d_in[2];
    const float* Wh   = (const float*)d_in[3];
    const float* bh   = (const float*)d_in[4];
    const float* Wv   = (const float*)d_in[5];
    const float* bv   = (const float*)d_in[6];
    const float* Wl   = (const float*)d_in[7];
    const float* bl   = (const float*)d_in[8];
    const float* cw0  = (const float*)d_in[9];
    const float* cb0  = (const float*)d_in[10];
    const float* cw1  = (const float*)d_in[11];
    const float* cb1  = (const float*)d_in[12];
    const float* cw2  = (const float*)d_in[13];
    const float* cb2  = (const float*)d_in[14];
    const float* Wc   = (const float*)d_in[15];
    const float* bc   = (const float*)d_in[16];

    float* ws   = (float*)d_ws;
    float* Apre = ws;                     // 65536
    float* g    = Apre + 65536;           // 131072
    float* x    = g + 131072;             // 131072
    float* cnn  = x + 131072;             // 3072
    float* part = cnn + 3072;             // 1572864 (96*2*64*128)
    float* wt0  = part + 1572864;         // 163840
    float* wt1  = wt0 + 163840;           // 131072
    float* wt2  = wt1 + 131072;           // 98304
    __bf16* bfb    = (__bf16*)(wt2 + 98304);
    __bf16* Whbf   = bfb;                 // 1048576
    __bf16* Wlbf   = bfb + 1048576;       // 262144
    __bf16* feat2b = bfb + 1310720;       // 393216 (512*768)
    __bf16* h2b    = bfb + 1703936;       // 524288
    // total ~13.7 MB of d_ws

    dim3 blk(256);
    cvt_kernel<<<6656, blk, 0, stream>>>(Wh, Wl, cw0, cw1, cw2, Whbf, Wlbf, wt0, wt1, wt2);
    // Apre = q @ W1^T + b_hidden (fp32 exact)
    gemm_tn_kernel<<<dim3(16, 1), blk, 0, stream>>>(q, 256, Wh, 1024, bh, Apre, 1024, 256);
    // pipelined MFMA attn (K=768)
    attn_kernel<<<512, blk, 0, stream>>>(q, ctx, mask, Whbf, Wv, bv, Apre, g);
    // feat2 (768 cols), h2 = tanh(feat2 @ Wh[:,256:]^T + Apre[c]), x = h2 @ Wl^T + bl
    feat2_kernel<<<512, blk, 0, stream>>>(q, g, feat2b);
    mfma_gemm_kernel<1, 1, 1><<<dim3(16, 8), blk, 0, stream>>>(
        feat2b, 768, Whbf + 256, 1024, Apre, h2b, 768, 1024);
    mfma_gemm_kernel<0, 0, 0><<<dim3(4, 8), blk, 0, stream>>>(
        h2b, 1024, Wlbf, 1024, bl, x, 1024, 256);
    // conv partials + reduce/pool + final FC
    conv_partial_kernel<<<96, blk, 0, stream>>>(x, wt0, wt1, wt2, part);
    reduce_pool_kernel<<<24, 128, 0, stream>>>(part, cb0, cb1, cb2, cnn);
    final_kernel<<<1, 320, 0, stream>>>(cnn, Wc, bc, (float*)d_out);
}

// Round 5
// 337.741 us; speedup vs baseline: 1.9307x; 1.9307x over previous
//
#include <hip/hip_runtime.h>
#include <math.h>

// B=8, C=64, T=128, E=256, 4E=1024, TYPE_NUM=40, NF=128
// h_pre[b,c,t,:] = Apre[c,:] + [ctx, |q-ctx|, q*ctx] @ Wh[:,256:1024]^T (K=768 MFMA)
// attn v6: async global_load_lds staging (W tiles + ctx tiles pre-swizzled in
// global: granule kg stored at position kg^(row&7), so unpadded LDS + XOR-swizzled
// ds_read_b128 is bank-conflict-free). No register prefetch (r4's spill lesson).

typedef __bf16 bf16x8 __attribute__((ext_vector_type(8)));
typedef float  f32x4  __attribute__((ext_vector_type(4)));

__device__ __forceinline__ float ftanh(float v) {
    float t = __expf(2.f * v);
    return 1.f - 2.f * __builtin_amdgcn_rcpf(t + 1.f);
}

// async 16B/lane global->LDS copy: lds dest must be wave-uniform; lane i lands
// at l + i*16B. g is per-lane.
__device__ __forceinline__ void gld_lds16(const __bf16* g, __bf16* l) {
    __builtin_amdgcn_global_load_lds(
        (const __attribute__((address_space(1))) void*)g,
        (__attribute__((address_space(3))) void*)l, 16, 0, 0);
}

// ---------------- fp32 tiled GEMM (only for Apre: M=64,N=1024,K=256) ----------------
__global__ __launch_bounds__(256) void gemm_tn_kernel(
    const float* __restrict__ A, int lda,
    const float* __restrict__ B, int ldb,
    const float* __restrict__ bias,
    float* __restrict__ C, int ldc, int K)
{
    __shared__ float As[16][68];
    __shared__ float Bs[16][68];
    const int tid = threadIdx.x;
    const int m0 = blockIdx.y * 64, n0 = blockIdx.x * 64;
    const int tm = tid >> 4, tn = tid & 15;
    const int lr = tid >> 2;
    const int lc = (tid & 3) * 4;

    float acc[4][4];
#pragma unroll
    for (int i = 0; i < 4; ++i)
#pragma unroll
        for (int j = 0; j < 4; ++j) acc[i][j] = 0.f;

    for (int k0 = 0; k0 < K; k0 += 16) {
        float4 av = *reinterpret_cast<const float4*>(A + (size_t)(m0 + lr) * lda + k0 + lc);
        float4 bv = *reinterpret_cast<const float4*>(B + (size_t)(n0 + lr) * ldb + k0 + lc);
        As[lc + 0][lr] = av.x; As[lc + 1][lr] = av.y; As[lc + 2][lr] = av.z; As[lc + 3][lr] = av.w;
        Bs[lc + 0][lr] = bv.x; Bs[lc + 1][lr] = bv.y; Bs[lc + 2][lr] = bv.z; Bs[lc + 3][lr] = bv.w;
        __syncthreads();
#pragma unroll
        for (int kk = 0; kk < 16; ++kk) {
            float4 a = *reinterpret_cast<const float4*>(&As[kk][tm * 4]);
            float4 b = *reinterpret_cast<const float4*>(&Bs[kk][tn * 4]);
            float ar[4] = {a.x, a.y, a.z, a.w};
            float br[4] = {b.x, b.y, b.z, b.w};
#pragma unroll
            for (int i = 0; i < 4; ++i)
#pragma unroll
                for (int j = 0; j < 4; ++j) acc[i][j] += ar[i] * br[j];
        }
        __syncthreads();
    }

#pragma unroll
    for (int i = 0; i < 4; ++i) {
        int m = m0 + tm * 4 + i;
        float vals[4];
#pragma unroll
        for (int j = 0; j < 4; ++j) {
            int n = n0 + tn * 4 + j;
            vals[j] = acc[i][j] + (bias ? bias[n] : 0.f);
        }
        float4 o; o.x = vals[0]; o.y = vals[1]; o.z = vals[2]; o.w = vals[3];
        *reinterpret_cast<float4*>(C + (size_t)m * ldc + n0 + tn * 4) = o;
    }
}

// ---------------- one-shot conversions ----------------
// A: Whbf flat [1024][1024] bf16 (for h2 GEMM)
// B: Whbf_t tiled+swizzled: [nc(4)][kc(12)][row(256)][g(8)] granule g'=kg^(row&7)
//    holds Wh[nc*256+row][256+kc*64+kg*8 .. +8]
// C: Wlbf [256][1024] bf16
// D: ctxbf_t tiled+swizzled: [b(8)][ec(4)][t(128)][g(8)], g'=kg^(t&7),
//    holds ctx[b][t][ec*64+kg*8 .. +8]
// E/F/G: conv weights transposed wtX[(e*KW+i)*128+f]
__global__ void cvt_kernel(const float* __restrict__ Wh, const float* __restrict__ Wl,
                           const float* __restrict__ ctx,
                           const float* __restrict__ cw0, const float* __restrict__ cw1,
                           const float* __restrict__ cw2,
                           __bf16* __restrict__ Whbf, __bf16* __restrict__ Whbf_t,
                           __bf16* __restrict__ Wlbf, __bf16* __restrict__ ctxbf_t,
                           float* __restrict__ wt0, float* __restrict__ wt1,
                           float* __restrict__ wt2)
{
    int idx = blockIdx.x * 256 + threadIdx.x;   // < 1835008
    if (idx < 1048576) { Whbf[idx] = (__bf16)Wh[idx]; return; }
    if (idx < 1146880) {                         // B: 98304 granules
        int di = idx - 1048576;
        int nc = di / 24576, rem = di - nc * 24576;
        int kc = rem >> 11, row = (rem >> 3) & 255, kgp = rem & 7;
        int kg = kgp ^ (row & 7);
        const float* s = Wh + (size_t)(nc * 256 + row) * 1024 + 256 + kc * 64 + kg * 8;
        bf16x8 u;
#pragma unroll
        for (int i = 0; i < 8; ++i) u[i] = (__bf16)s[i];
        *reinterpret_cast<bf16x8*>(Whbf_t + (size_t)di * 8) = u;
        return;
    }
    if (idx < 1409024) { int j = idx - 1146880; Wlbf[j] = (__bf16)Wl[j]; return; }
    if (idx < 1441792) {                         // D: 32768 granules
        int di = idx - 1409024;
        int b = di >> 12, ec = (di >> 10) & 3, t = (di >> 3) & 127, kgp = di & 7;
        int kg = kgp ^ (t & 7);
        const float* s = ctx + (size_t)(b * 128 + t) * 256 + ec * 64 + kg * 8;
        bf16x8 u;
#pragma unroll
        for (int i = 0; i < 8; ++i) u[i] = (__bf16)s[i];
        *reinterpret_cast<bf16x8*>(ctxbf_t + (size_t)di * 8) = u;
        return;
    }
    if (idx < 1605632) {
        int j = idx - 1441792; int f = j & 127, rest = j >> 7;
        int i = rest % 5, e = rest / 5;
        wt0[j] = cw0[(size_t)(f * 256 + e) * 5 + i]; return;
    }
    if (idx < 1736704) {
        int j = idx - 1605632; int f = j & 127, rest = j >> 7;
        int i = rest & 3, e = rest >> 2;
        wt1[j] = cw1[(size_t)(f * 256 + e) * 4 + i]; return;
    }
    {
        int j = idx - 1736704; int f = j & 127, rest = j >> 7;
        int i = rest % 3, e = rest / 3;
        wt2[j] = cw2[(size_t)(f * 256 + e) * 3 + i];
    }
}

// ---------------- attn v6: async-staged bf16-MFMA K=768 + tanh + Wv + softmax + g ---
__global__ __launch_bounds__(256, 2) void attn_kernel(
    const float* __restrict__ q,        // [64][256]
    const float* __restrict__ ctx,      // [8][128][256] fp32
    const __bf16* __restrict__ ctxbf_t, // tiled+swizzled bf16 ctx
    const int*   __restrict__ mask,     // [8][128]
    const __bf16* __restrict__ Whbf_t,  // tiled+swizzled bf16 W-pair
    const float* __restrict__ Wv,       // [1024]
    const float* __restrict__ bv,       // [1]
    const float* __restrict__ Apre,     // [64][1024] (includes b_hidden)
    float* __restrict__ g)              // [512][256]
{
    __shared__ __bf16 Us[128 * 64];     // unpadded; swizzle in granule position
    __shared__ __bf16 Ws[256 * 64];
    __shared__ float qc[256];
    __shared__ float sc[128];
    __shared__ float red;

    const int tid = threadIdx.x;
    const int b = blockIdx.x >> 6, c = blockIdx.x & 63;
    const int wave = tid >> 6, lane = tid & 63;
    const int w0 = wave >> 1, w1 = wave & 1;
    const int m0 = w0 * 64;
    const int l15 = lane & 15, quad = lane >> 4;
    const int swz = l15 & 7;            // row&7 for all our frag rows

    qc[tid] = q[c * 256 + tid];
    if (tid < 128) sc[tid] = 0.f;
    __syncthreads();

    for (int nc = 0; nc < 4; ++nc) {
        f32x4 acc[4][8];
#pragma unroll
        for (int mi = 0; mi < 4; ++mi)
#pragma unroll
            for (int ni = 0; ni < 8; ++ni) acc[mi][ni] = (f32x4){0.f, 0.f, 0.f, 0.f};

        for (int kc = 0; kc < 12; ++kc) {
            __syncthreads();            // prior MFMA reads done before overwrite
            // ---- W tile: 2048 granules async, 512 per wave ----
            const __bf16* wtile = Whbf_t + (size_t)(nc * 12 + kc) * 16384;
#pragma unroll
            for (int it = 0; it < 8; ++it) {
                int gidx = wave * 512 + it * 64;   // + lane inside
                gld_lds16(wtile + (size_t)(gidx + lane) * 8, &Ws[gidx * 8]);
            }
            const int region = kc >> 2;            // 0: ctx copy, 1: abs, 2: mul
            const int ec = kc & 3;
            if (region == 0) {
                // ---- U tile: 1024 granules async, 256 per wave ----
                const __bf16* ctile = ctxbf_t + (size_t)(b * 4 + ec) * 8192;
#pragma unroll
                for (int it = 0; it < 4; ++it) {
                    int gidx = wave * 256 + it * 64;
                    gld_lds16(ctile + (size_t)(gidx + lane) * 8, &Us[gidx * 8]);
                }
            } else {
                const bool isabs = (region == 1);
                const int e0 = ec * 64;
#pragma unroll
                for (int it = 0; it < 4; ++it) {
                    int idx = tid + it * 256;      // 1024 granules
                    int t = idx >> 3, kg = idx & 7;
                    int eb = e0 + kg * 8;
                    const float* cp = ctx + (size_t)(b * 128 + t) * 256 + eb;
                    float4 c0 = *reinterpret_cast<const float4*>(cp);
                    float4 c1 = *reinterpret_cast<const float4*>(cp + 4);
                    float cv[8] = {c0.x, c0.y, c0.z, c0.w, c1.x, c1.y, c1.z, c1.w};
                    bf16x8 u;
#pragma unroll
                    for (int i = 0; i < 8; ++i) {
                        float qv = qc[eb + i];
                        float x = isabs ? fabsf(qv - cv[i]) : qv * cv[i];
                        u[i] = (__bf16)x;
                    }
                    *reinterpret_cast<bf16x8*>(&Us[t * 64 + (kg ^ (t & 7)) * 8]) = u;
                }
            }
            __syncthreads();            // drains vmcnt (async) + lgkm (writes)
            // ---- MFMA on staged chunk ----
#pragma unroll
            for (int ks = 0; ks < 2; ++ks) {
                const int c8 = (((ks * 4 + quad) ^ swz)) * 8;
                bf16x8 a[4], bf[8];
#pragma unroll
                for (int mi = 0; mi < 4; ++mi)
                    a[mi] = *reinterpret_cast<const bf16x8*>(
                        &Us[(m0 + mi * 16 + l15) * 64 + c8]);
#pragma unroll
                for (int ni = 0; ni < 8; ++ni)
                    bf[ni] = *reinterpret_cast<const bf16x8*>(
                        &Ws[(w1 * 128 + ni * 16 + l15) * 64 + c8]);
#pragma unroll
                for (int mi = 0; mi < 4; ++mi)
#pragma unroll
                    for (int ni = 0; ni < 8; ++ni)
                        acc[mi][ni] = __builtin_amdgcn_mfma_f32_16x16x32_bf16(
                            a[mi], bf[ni], acc[mi][ni], 0, 0, 0);
            }
        }

        // ---- epilogue: h = ftanh(acc + Apre), partial score = h . Wv ----
        const int jcol = nc * 256 + w1 * 128 + l15;
        float av[8], wv[8];
#pragma unroll
        for (int ni = 0; ni < 8; ++ni) {
            av[ni] = Apre[c * 1024 + jcol + ni * 16];
            wv[ni] = Wv[jcol + ni * 16];
        }
#pragma unroll
        for (int mi = 0; mi < 4; ++mi) {
            const int tbase = m0 + mi * 16 + quad * 4;
            float p[4];
#pragma unroll
            for (int r = 0; r < 4; ++r) {
                float s = 0.f;
#pragma unroll
                for (int ni = 0; ni < 8; ++ni)
                    s += ftanh(acc[mi][ni][r] + av[ni]) * wv[ni];
                p[r] = s;
            }
#pragma unroll
            for (int off = 1; off < 16; off <<= 1)
#pragma unroll
                for (int r = 0; r < 4; ++r) p[r] += __shfl_xor(p[r], off, 16);
            if (l15 == 0) {
#pragma unroll
                for (int r = 0; r < 4; ++r) atomicAdd(&sc[tbase + r], p[r]);
            }
        }
        __syncthreads();                // epilogue done before next nc staging
    }

    // mask + b_v, softmax over t
    if (tid < 128) {
        float s = sc[tid] + bv[0];
        if (mask[b * 128 + tid] < 1) s = -1e10f;
        sc[tid] = s;
    }
    __syncthreads();
    if (tid < 64) {
        float m = fmaxf(sc[tid], sc[tid + 64]);
        for (int off = 32; off; off >>= 1) m = fmaxf(m, __shfl_xor(m, off, 64));
        if (tid == 0) red = m;
    }
    __syncthreads();
    const float mx = red;
    if (tid < 128) sc[tid] = __expf(sc[tid] - mx);
    __syncthreads();
    if (tid < 64) {
        float s = sc[tid] + sc[tid + 64];
        for (int off = 32; off; off >>= 1) s += __shfl_xor(s, off, 64);
        if (tid == 0) red = s;
    }
    __syncthreads();
    const float inv = 1.f / red;

    float gv = 0.f;
    for (int t = 0; t < 128; ++t) gv += sc[t] * ctx[(size_t)(b * 128 + t) * 256 + tid];
    g[(size_t)blockIdx.x * 256 + tid] = gv * inv;
}

// ---------------- feat2 = [g, |q-g|, q*g] (768 cols, bf16) ----------------
__global__ void feat2_kernel(const float* __restrict__ q, const float* __restrict__ g,
                             __bf16* __restrict__ feat2)
{
    int row = blockIdx.x, e = threadIdx.x;
    int c = row & 63;
    float qv = q[c * 256 + e], gv = g[row * 256 + e];
    __bf16* o = feat2 + (size_t)row * 768 + e;
    o[0]   = (__bf16)gv;
    o[256] = (__bf16)fabsf(qv - gv);
    o[512] = (__bf16)(qv * gv);
}

// ---------------- bf16 MFMA GEMM: C = act(A @ B^T + bias), 64x64 tile ----------------
// BMODE 0: bias[col]; BMODE 1: bias[(row&63)*1024 + col] (Apre-style)
template <int ACT, int OUTBF, int BMODE>
__global__ __launch_bounds__(256) void mfma_gemm_kernel(
    const __bf16* __restrict__ A, int lda,
    const __bf16* __restrict__ B, int ldb,
    const float* __restrict__ bias, void* __restrict__ Cout,
    int K, int ldc)
{
    __shared__ __bf16 As[64 * 72];
    __shared__ __bf16 Bs[64 * 72];
    const int tid = threadIdx.x;
    const int wave = tid >> 6, lane = tid & 63;
    const int w0 = wave >> 1, w1 = wave & 1;
    const int l15 = lane & 15, quad = lane >> 4;
    const int m0 = blockIdx.y * 64, n0 = blockIdx.x * 64;

    f32x4 acc[2][2];
#pragma unroll
    for (int mi = 0; mi < 2; ++mi)
#pragma unroll
        for (int ni = 0; ni < 2; ++ni) acc[mi][ni] = (f32x4){0.f, 0.f, 0.f, 0.f};

    for (int k0 = 0; k0 < K; k0 += 64) {
        __syncthreads();
#pragma unroll
        for (int it = 0; it < 2; ++it) {
            int idx = tid + it * 256;
            int row = idx >> 3, kg = idx & 7;
            int4 va = *reinterpret_cast<const int4*>(A + (size_t)(m0 + row) * lda + k0 + kg * 8);
            *reinterpret_cast<int4*>(&As[row * 72 + kg * 8]) = va;
            int4 vb = *reinterpret_cast<const int4*>(B + (size_t)(n0 + row) * ldb + k0 + kg * 8);
            *reinterpret_cast<int4*>(&Bs[row * 72 + kg * 8]) = vb;
        }
        __syncthreads();
#pragma unroll
        for (int ks = 0; ks < 2; ++ks) {
            bf16x8 a[2], bb[2];
#pragma unroll
            for (int mi = 0; mi < 2; ++mi)
                a[mi] = *reinterpret_cast<const bf16x8*>(
                    &As[(w0 * 32 + mi * 16 + l15) * 72 + ks * 32 + quad * 8]);
#pragma unroll
            for (int ni = 0; ni < 2; ++ni)
                bb[ni] = *reinterpret_cast<const bf16x8*>(
                    &Bs[(w1 * 32 + ni * 16 + l15) * 72 + ks * 32 + quad * 8]);
#pragma unroll
            for (int mi = 0; mi < 2; ++mi)
#pragma unroll
                for (int ni = 0; ni < 2; ++ni)
                    acc[mi][ni] = __builtin_amdgcn_mfma_f32_16x16x32_bf16(
                        a[mi], bb[ni], acc[mi][ni], 0, 0, 0);
        }
    }

#pragma unroll
    for (int mi = 0; mi < 2; ++mi)
#pragma unroll
        for (int ni = 0; ni < 2; ++ni) {
            int col = n0 + w1 * 32 + ni * 16 + l15;
#pragma unroll
            for (int r = 0; r < 4; ++r) {
                int row = m0 + w0 * 32 + mi * 16 + quad * 4 + r;
                float bsv = (BMODE == 0) ? bias[col] : bias[(row & 63) * 1024 + col];
                float v = acc[mi][ni][r] + bsv;
                if (ACT) v = ftanh(v);
                if (OUTBF) ((__bf16*)Cout)[(size_t)row * ldc + col] = (__bf16)v;
                else       ((float*)Cout)[(size_t)row * ldc + col] = v;
            }
        }
}

// ---------------- conv: e-chunk partials ----------------
template <int KW>
__device__ __forceinline__ void conv_body(
    const float* __restrict__ x, const float* __restrict__ wt,
    float* __restrict__ part, int b, int chunk, int bi, float* xs)
{
    const int tid = threadIdx.x;
    const int f = tid & 127, esub = tid >> 7;
    const int e0 = chunk * 64;

#pragma unroll
    for (int it = 0; it < 16; ++it) {
        int idx = tid + it * 256;
        int e = idx & 63, p = idx >> 6;
        xs[e * 72 + p] = x[(size_t)(b * 64 + p) * 256 + e0 + e];
    }
    __syncthreads();

    float acc[64];
#pragma unroll
    for (int p = 0; p < 64; ++p) acc[p] = 0.f;

    for (int ei = 0; ei < 32; ++ei) {
        const int eL = esub * 32 + ei;
        float wreg[KW];
#pragma unroll
        for (int i = 0; i < KW; ++i)
            wreg[i] = wt[(size_t)((e0 + eL) * KW + i) * 128 + f];
        float xv[68];
#pragma unroll
        for (int k4 = 0; k4 < 17; ++k4) {
            float4 v = *reinterpret_cast<const float4*>(&xs[eL * 72 + k4 * 4]);
            xv[k4 * 4 + 0] = v.x; xv[k4 * 4 + 1] = v.y;
            xv[k4 * 4 + 2] = v.z; xv[k4 * 4 + 3] = v.w;
        }
#pragma unroll
        for (int i = 0; i < KW; ++i)
#pragma unroll
            for (int p = 0; p < 64; ++p)
                acc[p] = fmaf(wreg[i], xv[p + i], acc[p]);
    }

    float* op = part + ((size_t)(bi * 2 + esub)) * 8192 + f;
#pragma unroll
    for (int p = 0; p < 64; ++p) op[p * 128] = acc[p];
}

__global__ __launch_bounds__(256) void conv_partial_kernel(
    const float* __restrict__ x,
    const float* __restrict__ wt0, const float* __restrict__ wt1,
    const float* __restrict__ wt2, float* __restrict__ part)
{
    __shared__ float xs[64 * 72];
    const int bi = blockIdx.x;            // kw*32 + b*4 + chunk
    const int kw = bi >> 5, b = (bi >> 2) & 7, chunk = bi & 3;
    if (kw == 0)      conv_body<5>(x, wt0, part, b, chunk, bi, xs);
    else if (kw == 1) conv_body<4>(x, wt1, part, b, chunk, bi, xs);
    else              conv_body<3>(x, wt2, part, b, chunk, bi, xs);
}

__global__ __launch_bounds__(128) void reduce_pool_kernel(
    const float* __restrict__ part,
    const float* __restrict__ b0, const float* __restrict__ b1,
    const float* __restrict__ b2, float* __restrict__ cnn)
{
    const int bi = blockIdx.x;            // kw*8 + b
    const int kw = bi >> 3, b = bi & 7;
    const int f = threadIdx.x;
    const int KW = 5 - kw, P = 64 - KW + 1;
    const float bias = (kw == 0 ? b0 : kw == 1 ? b1 : b2)[f];
    float mx = 0.f;                        // relu floor
    for (int p = 0; p < P; ++p) {
        float s = 0.f;
#pragma unroll
        for (int c4 = 0; c4 < 4; ++c4)
#pragma unroll
            for (int es = 0; es < 2; ++es)
                s += part[((size_t)((kw * 32 + b * 4 + c4) * 2 + es)) * 8192 + p * 128 + f];
        s += bias;
        mx = fmaxf(mx, s);
    }
    cnn[b * 384 + kw * 128 + f] = mx;
}

__global__ void final_kernel(const float* __restrict__ cnn, const float* __restrict__ Wc,
                             const float* __restrict__ bc, float* __restrict__ out)
{
    int o = threadIdx.x;
    if (o >= 320) return;
    int b = o / 40, t = o - b * 40;
    float s = bc[t];
    for (int i = 0; i < 384; ++i) s += cnn[b * 384 + i] * Wc[t * 384 + i];
    out[o] = s;
}

extern "C" void kernel_launch(void* const* d_in, const int* in_sizes, int n_in,
                              void* d_out, int out_size, void* d_ws, size_t ws_size,
                              hipStream_t stream)
{
    (void)in_sizes; (void)n_in; (void)out_size; (void)ws_size;
    const float* q    = (const float*)d_in[0];
    const float* ctx  = (const float*)d_in[1];
    const int*   mask = (const int*)d_in[2];
    const float* Wh   = (const float*)d_in[3];
    const float* bh   = (const float*)d_in[4];
    const float* Wv   = (const float*)d_in[5];
    const float* bv   = (const float*)d_in[6];
    const float* Wl   = (const float*)d_in[7];
    const float* bl   = (const float*)d_in[8];
    const float* cw0  = (const float*)d_in[9];
    const float* cb0  = (const float*)d_in[10];
    const float* cw1  = (const float*)d_in[11];
    const float* cb1  = (const float*)d_in[12];
    const float* cw2  = (const float*)d_in[13];
    const float* cb2  = (const float*)d_in[14];
    const float* Wc   = (const float*)d_in[15];
    const float* bc   = (const float*)d_in[16];

    float* ws   = (float*)d_ws;
    float* Apre = ws;                     // 65536
    float* g    = Apre + 65536;           // 131072
    float* x    = g + 131072;             // 131072
    float* cnn  = x + 131072;             // 3072
    float* part = cnn + 3072;             // 1572864 (96*2*64*128)
    float* wt0  = part + 1572864;         // 163840
    float* wt1  = wt0 + 163840;           // 131072
    float* wt2  = wt1 + 131072;           // 98304
    __bf16* bfb    = (__bf16*)(wt2 + 98304);
    __bf16* Whbf   = bfb;                 // 1048576
    __bf16* Wlbf   = bfb + 1048576;       // 262144
    __bf16* feat2b = bfb + 1310720;       // 393216 (512*768)
    __bf16* h2b    = bfb + 1703936;       // 524288
    // Whbf_t + ctxbf_t alias `part` (disjoint lifetimes: cvt->attn vs conv->reduce)
    __bf16* Whbf_t = (__bf16*)part;       // 786432 bf16
    __bf16* ctxbf_t= Whbf_t + 786432;     // 262144 bf16 (total 2.1MB < part's 6.3MB)
    // total ~13.6 MB of d_ws

    dim3 blk(256);
    cvt_kernel<<<7168, blk, 0, stream>>>(Wh, Wl, ctx, cw0, cw1, cw2,
                                         Whbf, Whbf_t, Wlbf, ctxbf_t, wt0, wt1, wt2);
    // Apre = q @ W1^T + b_hidden (fp32 exact)
    gemm_tn_kernel<<<dim3(16, 1), blk, 0, stream>>>(q, 256, Wh, 1024, bh, Apre, 1024, 256);
    // async-staged MFMA attn (K=768)
    attn_kernel<<<512, blk, 0, stream>>>(q, ctx, ctxbf_t, mask, Whbf_t, Wv, bv, Apre, g);
    // feat2 (768 cols), h2 = tanh(feat2 @ Wh[:,256:]^T + Apre[c]), x = h2 @ Wl^T + bl
    feat2_kernel<<<512, blk, 0, stream>>>(q, g, feat2b);
    mfma_gemm_kernel<1, 1, 1><<<dim3(16, 8), blk, 0, stream>>>(
        feat2b, 768, Whbf + 256, 1024, Apre, h2b, 768, 1024);
    mfma_gemm_kernel<0, 0, 0><<<dim3(4, 8), blk, 0, stream>>>(
        h2b, 1024, Wlbf, 1024, bl, x, 1024, 256);
    // conv partials + reduce/pool + final FC
    conv_partial_kernel<<<96, blk, 0, stream>>>(x, wt0, wt1, wt2, part);
    reduce_pool_kernel<<<24, 128, 0, stream>>>(part, cb0, cb1, cb2, cnn);
    final_kernel<<<1, 320, 0, stream>>>(cnn, Wc, bc, (float*)d_out);
}